// Round 7
// baseline (122.076 us; speedup 1.0000x reference)
//
#include <hip/hip_runtime.h>
#include <hip/hip_bf16.h>

#define D_IN   246
#define NW     10
#define NG     4
#define NOUT   40
#define FANIN  256
#define BATCH  256
#define TSTEPS 64
#define NPAIR  123                       // K pairs (i = 2j, 2j+1)
#define WPK_ELEMS (NG * NPAIR * 20)      // 9840 floats: [g][j][o*2+k]

// ---------------- Kernel 0: pack W -> Wpk[g][j][o*2+k]  (80B per K-pair row) ----
__global__ __launch_bounds__(256) void k_wt(const float* __restrict__ W,
                                            float* __restrict__ Wpk) {
    int e = blockIdx.x * 256 + threadIdx.x;
    if (e >= WPK_ELEMS) return;
    int q = e % 20;            // o*2 + k
    int j = (e / 20) % NPAIR;
    int g = e / (20 * NPAIR);
    int o = q >> 1, k = q & 1;
    Wpk[e] = W[(g * NW + o) * FANIN + (2 * j + k)];
}

// ---------------- Kernel 1: GEMM  zxT[b][t][o][g] = x.W + bias + theta ----------
// grid (64 t, 4 bq), 512 thr = 8 waves: g = wv&3, kh = wv>>2 (K pair-split 62/61).
// W streamed via VECTOR loads (laundered pointer) -> deep vmcnt pipelining.
__global__ __launch_bounds__(512) void k_gemm(
    const float* __restrict__ x,      // (64,256,246)
    const float* __restrict__ Wpk,    // (4,123,20)
    const float* __restrict__ bias,   // (4,10)
    const float* __restrict__ theta,  // (4,10)
    float* __restrict__ zxT)          // (256,64,10,4)  b-major, gate-minor
{
    const int t    = blockIdx.x;
    const int bq   = blockIdx.y;
    const int tid  = threadIdx.x;
    const int lane = tid & 63;
    const int wv   = __builtin_amdgcn_readfirstlane(tid >> 6);
    const int g    = wv & 3;
    const int kh   = wv >> 2;

    __shared__ float xl[64 * D_IN];    // 62.98 KB
    __shared__ float pr[NG][64][NW];   // 10.24 KB (kh=1 partials)

    // stage x rows for these 64 b's (coalesced float2)
    const float* xsrc = x + ((size_t)t * BATCH + bq * 64) * D_IN;
    for (int k = tid; k < 64 * NPAIR; k += 512) {
        int row = k / NPAIR;
        int j   = k - row * NPAIR;
        float2 v = *reinterpret_cast<const float2*>(xsrc + row * D_IN + 2 * j);
        *reinterpret_cast<float2*>(xl + row * D_IN + 2 * j) = v;
    }
    __syncthreads();

    const int jstart = kh ? 62 : 0;
    const int npairs = kh ? 61 : 62;

    // launder W pointer into VGPRs -> forces vector (global_load) path
    unsigned long long wa = (unsigned long long)(Wpk + (g * NPAIR + jstart) * 20);
    asm("" : "+v"(wa));
    const float* wbase = (const float*)wa;

    float acc[NW];
#pragma unroll
    for (int o = 0; o < NW; ++o) acc[o] = 0.f;

    const float* xr = xl + lane * D_IN + 2 * jstart;

#pragma unroll 4
    for (int jj = 0; jj < npairs; ++jj) {
        float2 xv = *reinterpret_cast<const float2*>(xr + 2 * jj);
        const float4* w4 = reinterpret_cast<const float4*>(wbase + jj * 20);
        float4 wa0 = w4[0], wb = w4[1], wc = w4[2], wd = w4[3], we = w4[4];
        acc[0] = fmaf(xv.x, wa0.x, fmaf(xv.y, wa0.y, acc[0]));
        acc[1] = fmaf(xv.x, wa0.z, fmaf(xv.y, wa0.w, acc[1]));
        acc[2] = fmaf(xv.x, wb.x,  fmaf(xv.y, wb.y,  acc[2]));
        acc[3] = fmaf(xv.x, wb.z,  fmaf(xv.y, wb.w,  acc[3]));
        acc[4] = fmaf(xv.x, wc.x,  fmaf(xv.y, wc.y,  acc[4]));
        acc[5] = fmaf(xv.x, wc.z,  fmaf(xv.y, wc.w,  acc[5]));
        acc[6] = fmaf(xv.x, wd.x,  fmaf(xv.y, wd.y,  acc[6]));
        acc[7] = fmaf(xv.x, wd.z,  fmaf(xv.y, wd.w,  acc[7]));
        acc[8] = fmaf(xv.x, we.x,  fmaf(xv.y, we.y,  acc[8]));
        acc[9] = fmaf(xv.x, we.z,  fmaf(xv.y, we.w,  acc[9]));
    }

    if (kh == 1) {
#pragma unroll
        for (int o = 0; o < NW; ++o) pr[g][lane][o] = acc[o];
    }
    __syncthreads();

    if (kh == 0) {
        const int b = bq * 64 + lane;
        float* zo = zxT + ((size_t)b * TSTEPS + t) * NOUT + g;
#pragma unroll
        for (int o = 0; o < NW; ++o) {
            float v = acc[o] + pr[g][lane][o] + bias[g * NW + o] + theta[g * NW + o];
            zo[o * NG] = v;   // [b][t][o][g]
        }
    }
}

// ---------------- Kernel 2: 64-step scan, 1 wave per b, all gates in-lane -------
template <int CTRL>
__device__ __forceinline__ float dpp_shr_mul(float p) {
    int up = __builtin_amdgcn_update_dpp(__float_as_int(1.0f), __float_as_int(p),
                                         CTRL, 0xF, 0xF, false);
    return p * __int_as_float(up);
}

__global__ __launch_bounds__(64) void k_scan(
    const float* __restrict__ zxT,  // (256,64,10,4)
    const float* __restrict__ W,    // (4,10,256): recurrent cols 246..255
    float* __restrict__ out,        // (64,256,10)
    float* __restrict__ hxout,      // (256,10)
    float* __restrict__ cxout)      // (256,10)
{
    const int b    = blockIdx.x;
    const int lane = threadIdx.x;
    const int o16  = lane & 15;
    const int oc   = (o16 < NW) ? o16 : 0;

    __shared__ float zl[TSTEPS * NOUT];   // 10.24 KB, [t][o][g]

    {   // coalesced stage (640 float4s, 10 per lane)
        const float4* s4 = reinterpret_cast<const float4*>(zxT + (size_t)b * TSTEPS * NOUT);
        float4* d4 = reinterpret_cast<float4*>(zl);
#pragma unroll
        for (int q = 0; q < 10; ++q) d4[q * 64 + lane] = s4[q * 64 + lane];
    }

    // recurrent weights for all 4 gates of this lane's o (latency hides under stage)
    float wh[NG][NW];
#pragma unroll
    for (int gg = 0; gg < NG; ++gg)
#pragma unroll
        for (int j = 0; j < NW; ++j)
            wh[gg][j] = W[(gg * NW + oc) * FANIN + D_IN + j];

    __syncthreads();

    float hx_s[NW];
#pragma unroll
    for (int j = 0; j < NW; ++j) hx_s[j] = 0.f;
    float cx = 0.f, hv = 0.f;

    const float* zrow = zl + oc * NG;
    float4 zn = *reinterpret_cast<const float4*>(zrow);      // t = 0
    float* outp = out + (size_t)b * NW + oc;

    for (int t = 0; t < TSTEPS; ++t) {
        float4 zc4 = zn;
        zn = *reinterpret_cast<const float4*>(zrow + ((t + 1) & 63) * NOUT); // off-chain

        float z0 = zc4.x, z1 = zc4.y, z2 = zc4.z, z3 = zc4.w;
#pragma unroll
        for (int j = 0; j < NW; ++j) {
            z0 = fmaf(hx_s[j], wh[0][j], z0);
            z1 = fmaf(hx_s[j], wh[1][j], z1);
            z2 = fmaf(hx_s[j], wh[2][j], z2);
            z3 = fmaf(hx_s[j], wh[3][j], z3);
        }

        float p0 = __cosf(z0), p1 = __cosf(z1), p2 = __cosf(z2), p3 = __cosf(z3);

        p0 = dpp_shr_mul<0x111>(p0); p1 = dpp_shr_mul<0x111>(p1);
        p2 = dpp_shr_mul<0x111>(p2); p3 = dpp_shr_mul<0x111>(p3);
        p0 = dpp_shr_mul<0x112>(p0); p1 = dpp_shr_mul<0x112>(p1);
        p2 = dpp_shr_mul<0x112>(p2); p3 = dpp_shr_mul<0x112>(p3);
        p0 = dpp_shr_mul<0x114>(p0); p1 = dpp_shr_mul<0x114>(p1);
        p2 = dpp_shr_mul<0x114>(p2); p3 = dpp_shr_mul<0x114>(p3);
        p0 = dpp_shr_mul<0x118>(p0); p1 = dpp_shr_mul<0x118>(p1);
        p2 = dpp_shr_mul<0x118>(p2); p3 = dpp_shr_mul<0x118>(p3);

        float fg  = __fdividef(1.f, 1.f + __expf(-p0));
        float ig  = __fdividef(1.f, 1.f + __expf(-p1));
        float gg2 = 2.f * __fdividef(1.f, 1.f + __expf(-2.f * p2)) - 1.f;
        float og  = __fdividef(1.f, 1.f + __expf(-p3));

        cx = fmaf(fg, cx, ig * gg2);
        float e2 = __expf(cx + cx);
        float th = 1.f - __fdividef(2.f, 1.f + e2);
        hv = og * th;

        if (lane < NW) outp[(size_t)t * (BATCH * NW)] = hv;

#pragma unroll
        for (int j = 0; j < NW; ++j)
            hx_s[j] = __int_as_float(__builtin_amdgcn_readlane(__float_as_int(hv), j));
    }

    if (lane < NW) {
        hxout[b * NW + lane] = hv;
        cxout[b * NW + lane] = cx;
    }
}

extern "C" void kernel_launch(void* const* d_in, const int* in_sizes, int n_in,
                              void* d_out, int out_size, void* d_ws, size_t ws_size,
                              hipStream_t stream) {
    const float* x     = (const float*)d_in[0];  // (64,256,246)
    const float* W     = (const float*)d_in[1];  // (4,10,256)
    const float* bias  = (const float*)d_in[2];  // (4,10)
    const float* theta = (const float*)d_in[3];  // (4,10)

    float* out   = (float*)d_out;                        // (64,256,10)
    float* hxout = out + (size_t)TSTEPS * BATCH * NW;    // (256,10)
    float* cxout = hxout + (size_t)BATCH * NW;           // (256,10)

    float* Wpk = (float*)d_ws;                 // 9840 floats
    float* zxT = Wpk + WPK_ELEMS;              // (256,64,40) = 2.62 MB

    k_wt<<<(WPK_ELEMS + 255) / 256, 256, 0, stream>>>(W, Wpk);
    dim3 g1(TSTEPS, 4);
    k_gemm<<<g1, 512, 0, stream>>>(x, Wpk, bias, theta, zxT);
    k_scan<<<BATCH, 64, 0, stream>>>(zxT, W, out, hxout, cxout);
}

// Round 8
// 120.887 us; speedup vs baseline: 1.0098x; 1.0098x over previous
//
#include <hip/hip_runtime.h>
#include <hip/hip_bf16.h>

#define D_IN   246
#define NW     10
#define NG     4
#define NOUT   40
#define FANIN  256
#define BATCH  256
#define TSTEPS 64
#define NPAIR  123                       // K pairs (i = 2j, 2j+1)
#define WPK_ELEMS (NG * NPAIR * 20)      // 9840 floats: [g][j][o*2+k]

// ---------------- Kernel 0: pack W -> Wpk[g][j][o*2+k]  (80B per K-pair row) ----
__global__ __launch_bounds__(256) void k_wt(const float* __restrict__ W,
                                            float* __restrict__ Wpk) {
    int e = blockIdx.x * 256 + threadIdx.x;
    if (e >= WPK_ELEMS) return;
    int q = e % 20;            // o*2 + k
    int j = (e / 20) % NPAIR;
    int g = e / (20 * NPAIR);
    int o = q >> 1, k = q & 1;
    Wpk[e] = W[(g * NW + o) * FANIN + (2 * j + k)];
}

template <int CTRL>
__device__ __forceinline__ float dpp_shr_mul(float p) {
    int up = __builtin_amdgcn_update_dpp(__float_as_int(1.0f), __float_as_int(p),
                                         CTRL, 0xF, 0xF, false);
    return p * __int_as_float(up);
}

// ---------------- Fused kernel: one block (512 thr, 8 waves) per batch element --
// A: stage x[.,b,.] into LDS.
// B: GEMM, wave=(g,kh) K-split, W streamed via VECTOR loads (deep vmcnt pipeline),
//    results to zl[t][o][g] in LDS.
// C: wave 0 runs the 64-step scan, all 4 gates in-lane (lane=o), VALU-only chain.
__global__ __launch_bounds__(512) void k_fused(
    const float* __restrict__ x,      // (64,256,246)
    const float* __restrict__ Wpk,    // (4,123,20)
    const float* __restrict__ bias,   // (4,10)
    const float* __restrict__ theta,  // (4,10)
    const float* __restrict__ W,      // (4,10,256): recurrent cols 246..255
    float* __restrict__ out,          // (64,256,10)
    float* __restrict__ hxout,        // (256,10)
    float* __restrict__ cxout)        // (256,10)
{
    const int b    = blockIdx.x;
    const int tid  = threadIdx.x;
    const int lane = tid & 63;
    const int wv   = __builtin_amdgcn_readfirstlane(tid >> 6);
    const int g    = wv & 3;
    const int kh   = wv >> 2;

    __shared__ float xl[64 * D_IN];       // 62.98 KB
    __shared__ float pr[NG][64][NW];      // 10.24 KB (kh=1 partials)
    __shared__ float zl[TSTEPS * NOUT];   // 10.24 KB [t][o][g]

    // ---- wave-0 preload of recurrent weights (latency hides under staging) ----
    const int o16 = lane & 15;
    const int oc  = (o16 < NW) ? o16 : 0;
    float wh[NG][NW];
    if (wv == 0) {
#pragma unroll
        for (int gg = 0; gg < NG; ++gg)
#pragma unroll
            for (int j = 0; j < NW; ++j)
                wh[gg][j] = W[(gg * NW + oc) * FANIN + D_IN + j];
    }

    // ---- Phase A: stage x rows (8 rows/wave, coalesced float2) ----
    for (int row = wv; row < 64; row += 8) {
        const float* src = x + ((size_t)row * BATCH + b) * D_IN;
        float* dst = xl + row * D_IN;
        for (int j = lane; j < 123; j += 64) {
            float2 v = *reinterpret_cast<const float2*>(src + 2 * j);
            *reinterpret_cast<float2*>(dst + 2 * j) = v;
        }
    }
    __syncthreads();

    // ---- Phase B: zx GEMM, K pair-split (62/61), vector W stream ----
    {
        const int jstart = kh ? 62 : 0;
        const int npairs = kh ? 61 : 62;

        // launder W pointer into VGPRs -> forces vector (global_load) path
        unsigned long long wa = (unsigned long long)(Wpk + (g * NPAIR + jstart) * 20);
        asm("" : "+v"(wa));
        const float* wbase = (const float*)wa;

        float acc[NW];
#pragma unroll
        for (int o = 0; o < NW; ++o) acc[o] = 0.f;

        const float* xr = xl + lane * D_IN + 2 * jstart;   // lane = t

#pragma unroll 4
        for (int jj = 0; jj < npairs; ++jj) {
            float2 xv = *reinterpret_cast<const float2*>(xr + 2 * jj);
            const float4* w4 = reinterpret_cast<const float4*>(wbase + jj * 20);
            float4 wa0 = w4[0], wb = w4[1], wc = w4[2], wd = w4[3], we = w4[4];
            acc[0] = fmaf(xv.x, wa0.x, fmaf(xv.y, wa0.y, acc[0]));
            acc[1] = fmaf(xv.x, wa0.z, fmaf(xv.y, wa0.w, acc[1]));
            acc[2] = fmaf(xv.x, wb.x,  fmaf(xv.y, wb.y,  acc[2]));
            acc[3] = fmaf(xv.x, wb.z,  fmaf(xv.y, wb.w,  acc[3]));
            acc[4] = fmaf(xv.x, wc.x,  fmaf(xv.y, wc.y,  acc[4]));
            acc[5] = fmaf(xv.x, wc.z,  fmaf(xv.y, wc.w,  acc[5]));
            acc[6] = fmaf(xv.x, wd.x,  fmaf(xv.y, wd.y,  acc[6]));
            acc[7] = fmaf(xv.x, wd.z,  fmaf(xv.y, wd.w,  acc[7]));
            acc[8] = fmaf(xv.x, we.x,  fmaf(xv.y, we.y,  acc[8]));
            acc[9] = fmaf(xv.x, we.z,  fmaf(xv.y, we.w,  acc[9]));
        }

        if (kh == 1) {
#pragma unroll
            for (int o = 0; o < NW; ++o) pr[g][lane][o] = acc[o];
        }
        __syncthreads();

        if (kh == 0) {
#pragma unroll
            for (int o = 0; o < NW; ++o) {
                float v = acc[o] + pr[g][lane][o] + bias[g * NW + o] + theta[g * NW + o];
                zl[lane * NOUT + o * NG + g] = v;   // [t][o][g]
            }
        }
    }
    __syncthreads();
    if (wv != 0) return;

    // ---- Phase C: 64-step scan, all gates in-lane, VALU-only chain ----
    float hx_s[NW];
#pragma unroll
    for (int j = 0; j < NW; ++j) hx_s[j] = 0.f;
    float cx = 0.f, hv = 0.f;

    const float* zrow = zl + oc * NG;
    float4 zn = *reinterpret_cast<const float4*>(zrow);      // t = 0
    float* outp = out + (size_t)b * NW + oc;

    for (int t = 0; t < TSTEPS; ++t) {
        float4 zc4 = zn;
        zn = *reinterpret_cast<const float4*>(zrow + ((t + 1) & 63) * NOUT); // off-chain

        float z0 = zc4.x, z1 = zc4.y, z2 = zc4.z, z3 = zc4.w;
#pragma unroll
        for (int j = 0; j < NW; ++j) {
            z0 = fmaf(hx_s[j], wh[0][j], z0);
            z1 = fmaf(hx_s[j], wh[1][j], z1);
            z2 = fmaf(hx_s[j], wh[2][j], z2);
            z3 = fmaf(hx_s[j], wh[3][j], z3);
        }

        float p0 = __cosf(z0), p1 = __cosf(z1), p2 = __cosf(z2), p3 = __cosf(z3);

        p0 = dpp_shr_mul<0x111>(p0); p1 = dpp_shr_mul<0x111>(p1);
        p2 = dpp_shr_mul<0x111>(p2); p3 = dpp_shr_mul<0x111>(p3);
        p0 = dpp_shr_mul<0x112>(p0); p1 = dpp_shr_mul<0x112>(p1);
        p2 = dpp_shr_mul<0x112>(p2); p3 = dpp_shr_mul<0x112>(p3);
        p0 = dpp_shr_mul<0x114>(p0); p1 = dpp_shr_mul<0x114>(p1);
        p2 = dpp_shr_mul<0x114>(p2); p3 = dpp_shr_mul<0x114>(p3);
        p0 = dpp_shr_mul<0x118>(p0); p1 = dpp_shr_mul<0x118>(p1);
        p2 = dpp_shr_mul<0x118>(p2); p3 = dpp_shr_mul<0x118>(p3);

        float fg  = __fdividef(1.f, 1.f + __expf(-p0));
        float ig  = __fdividef(1.f, 1.f + __expf(-p1));
        float gg2 = 2.f * __fdividef(1.f, 1.f + __expf(-2.f * p2)) - 1.f;
        float og  = __fdividef(1.f, 1.f + __expf(-p3));

        cx = fmaf(fg, cx, ig * gg2);
        float e2 = __expf(cx + cx);
        float th = 1.f - __fdividef(2.f, 1.f + e2);
        hv = og * th;

        if (lane < NW) outp[(size_t)t * (BATCH * NW)] = hv;

#pragma unroll
        for (int j = 0; j < NW; ++j)
            hx_s[j] = __int_as_float(__builtin_amdgcn_readlane(__float_as_int(hv), j));
    }

    if (lane < NW) {
        hxout[b * NW + lane] = hv;
        cxout[b * NW + lane] = cx;
    }
}

extern "C" void kernel_launch(void* const* d_in, const int* in_sizes, int n_in,
                              void* d_out, int out_size, void* d_ws, size_t ws_size,
                              hipStream_t stream) {
    const float* x     = (const float*)d_in[0];  // (64,256,246)
    const float* W     = (const float*)d_in[1];  // (4,10,256)
    const float* bias  = (const float*)d_in[2];  // (4,10)
    const float* theta = (const float*)d_in[3];  // (4,10)

    float* out   = (float*)d_out;                        // (64,256,10)
    float* hxout = out + (size_t)TSTEPS * BATCH * NW;    // (256,10)
    float* cxout = hxout + (size_t)BATCH * NW;           // (256,10)

    float* Wpk = (float*)d_ws;                 // 9840 floats

    k_wt<<<(WPK_ELEMS + 255) / 256, 256, 0, stream>>>(W, Wpk);
    k_fused<<<BATCH, 512, 0, stream>>>(x, Wpk, bias, theta, W, out, hxout, cxout);
}

// Round 9
// 110.020 us; speedup vs baseline: 1.1096x; 1.0988x over previous
//
#include <hip/hip_runtime.h>
#include <hip/hip_bf16.h>

#define D_IN   246
#define NW     10
#define NG     4
#define NOUT   40
#define FANIN  256
#define BATCH  256
#define TSTEPS 64
#define NPAIR  123                 // K pairs (i = 2j, 2j+1)
#define WL_ELEMS (NG * NPAIR * 20) // 9840 floats: [g][j][o*2+k]

// ---------------- Kernel 1: GEMM  zxT[b][t][g][o] = x.W + bias + theta ----------
// grid (64 t, 4 bq), 512 thr = 8 waves: g = wv&3, kh = wv>>2 (K pair-split 62/61).
// W transposed into LDS once per block; read via uniform-address ds_read_b128
// (broadcast, conflict-free, ~60cy) instead of per-wave L2 streams (~400cy).
__global__ __launch_bounds__(512) void k_gemm(
    const float* __restrict__ x,      // (64,256,246)
    const float* __restrict__ W,      // (4,10,256)
    const float* __restrict__ bias,   // (4,10)
    const float* __restrict__ theta,  // (4,10)
    float* __restrict__ zxT)          // (256,64,4,10)  b-major
{
    const int t    = blockIdx.x;
    const int bq   = blockIdx.y;
    const int tid  = threadIdx.x;
    const int lane = tid & 63;
    const int wv   = __builtin_amdgcn_readfirstlane(tid >> 6);
    const int g    = wv & 3;
    const int kh   = wv >> 2;

    __shared__ float xl[64 * D_IN];        // 62976 B
    __shared__ float Wl[WL_ELEMS];         // 39360 B  [g][j][o*2+k]
    __shared__ float pr[NG][64][NW];       // 10240 B  (kh=1 partials)

    // stage + transpose W -> Wl (each thread ~20 scattered dword loads, pipelined)
    for (int e = tid; e < WL_ELEMS; e += 512) {
        int q = e % 20;                    // o*2 + k
        int j = (e / 20) % NPAIR;
        int gg = e / (20 * NPAIR);
        int o = q >> 1, k = q & 1;
        Wl[e] = W[(gg * NW + o) * FANIN + (2 * j + k)];
    }
    // stage x rows (coalesced float2)
    const float* xsrc = x + ((size_t)t * BATCH + bq * 64) * D_IN;
    for (int k = tid; k < 64 * NPAIR; k += 512) {
        int row = k / NPAIR;
        int j   = k - row * NPAIR;
        float2 v = *reinterpret_cast<const float2*>(xsrc + row * D_IN + 2 * j);
        *reinterpret_cast<float2*>(xl + row * D_IN + 2 * j) = v;
    }
    __syncthreads();

    const int jstart = kh ? 62 : 0;
    const int npairs = kh ? 61 : 62;

    float acc[NW];
#pragma unroll
    for (int o = 0; o < NW; ++o) acc[o] = 0.f;

    const float* wg = Wl + (g * NPAIR + jstart) * 20;   // LDS, uniform addr
    const float* xr = xl + lane * D_IN + 2 * jstart;    // lane = local b

#pragma unroll 2
    for (int jj = 0; jj < npairs; ++jj) {
        float2 xv = *reinterpret_cast<const float2*>(xr + 2 * jj);
        const float4* w4 = reinterpret_cast<const float4*>(wg + jj * 20);
        float4 wa0 = w4[0], wb = w4[1], wc = w4[2], wd = w4[3], we = w4[4];
        acc[0] = fmaf(xv.x, wa0.x, fmaf(xv.y, wa0.y, acc[0]));
        acc[1] = fmaf(xv.x, wa0.z, fmaf(xv.y, wa0.w, acc[1]));
        acc[2] = fmaf(xv.x, wb.x,  fmaf(xv.y, wb.y,  acc[2]));
        acc[3] = fmaf(xv.x, wb.z,  fmaf(xv.y, wb.w,  acc[3]));
        acc[4] = fmaf(xv.x, wc.x,  fmaf(xv.y, wc.y,  acc[4]));
        acc[5] = fmaf(xv.x, wc.z,  fmaf(xv.y, wc.w,  acc[5]));
        acc[6] = fmaf(xv.x, wd.x,  fmaf(xv.y, wd.y,  acc[6]));
        acc[7] = fmaf(xv.x, wd.z,  fmaf(xv.y, wd.w,  acc[7]));
        acc[8] = fmaf(xv.x, we.x,  fmaf(xv.y, we.y,  acc[8]));
        acc[9] = fmaf(xv.x, we.z,  fmaf(xv.y, we.w,  acc[9]));
    }

    if (kh == 1) {
#pragma unroll
        for (int o = 0; o < NW; ++o) pr[g][lane][o] = acc[o];
    }
    __syncthreads();

    if (kh == 0) {
        const int b = bq * 64 + lane;
        float* zo = zxT + ((size_t)b * TSTEPS + t) * NOUT + g * NW;
#pragma unroll
        for (int q = 0; q < 5; ++q) {
            float v0 = acc[2*q]   + pr[g][lane][2*q]   + bias[g*NW + 2*q]   + theta[g*NW + 2*q];
            float v1 = acc[2*q+1] + pr[g][lane][2*q+1] + bias[g*NW + 2*q+1] + theta[g*NW + 2*q+1];
            *reinterpret_cast<float2*>(zo + 2 * q) = make_float2(v0, v1);
        }
    }
}

// ---------------- Kernel 2: scan — 32 blocks x 8 waves, wave = batch element ----
// lane = (gate r, unit o). z from global with 1-step prefetch (no LDS).
// 2 waves/SIMD co-resident fill single-wave issue-cadence stalls.
template <int CTRL>
__device__ __forceinline__ float dpp_shr_mul(float p) {
    int up = __builtin_amdgcn_update_dpp(__float_as_int(1.0f), __float_as_int(p),
                                         CTRL, 0xF, 0xF, false);
    return p * __int_as_float(up);
}

__global__ __launch_bounds__(512) void k_scan(
    const float* __restrict__ zxT,  // (256,64,4,10)
    const float* __restrict__ W,    // (4,10,256): recurrent cols 246..255
    float* __restrict__ out,        // (64,256,10)
    float* __restrict__ hxout,      // (256,10)
    float* __restrict__ cxout)      // (256,10)
{
    const int wv   = __builtin_amdgcn_readfirstlane(threadIdx.x >> 6);
    const int b    = blockIdx.x * 8 + wv;
    const int lane = threadIdx.x & 63;
    const int r    = lane >> 4;      // gate row
    const int o    = lane & 15;
    const bool act = (o < NW);
    const int oc   = act ? o : 0;

    float wh[NW];
#pragma unroll
    for (int j = 0; j < NW; ++j)
        wh[j] = W[(r * NW + oc) * FANIN + D_IN + j];

    const float am = (r == 2) ? 2.f : 1.f;
    const float vm = (r == 2) ? 2.f : 1.f;
    const float vc = (r == 2) ? -1.f : 0.f;
    const int idx1 = (lane ^ 16) << 2;
    const int idx2 = (lane ^ 32) << 2;
    const int idx3 = (lane ^ 48) << 2;
    const bool q1 = (r & 1) != 0;
    const bool q2 = (r & 2) != 0;

    float hx_s[NW];
#pragma unroll
    for (int j = 0; j < NW; ++j) hx_s[j] = 0.f;
    float cx = 0.f, hv = 0.f;

    const float* zp = zxT + (size_t)b * TSTEPS * NOUT + r * NW + oc;
    float zc = zp[0];
    float* outp = out + (size_t)b * NW + oc;

    for (int t = 0; t < TSTEPS; ++t) {
        // off-chain prefetch of next step's pre-activation (L2, ~300cy hidden)
        float zn = zp[(t + 1) * NOUT];   // t=63 reads 160B past this b's slab (ws scratch, unused)

        float s0 = zc, s1 = 0.f;
#pragma unroll
        for (int j = 0; j < 5; ++j) {
            s0 = fmaf(hx_s[2 * j],     wh[2 * j],     s0);
            s1 = fmaf(hx_s[2 * j + 1], wh[2 * j + 1], s1);
        }
        float z = s0 + s1;

        float cv = __cosf(z);

        float p = cv;
        p = dpp_shr_mul<0x111>(p);
        p = dpp_shr_mul<0x112>(p);
        p = dpp_shr_mul<0x114>(p);
        p = dpp_shr_mul<0x118>(p);

        float e  = __expf(-(p * am));
        float sg = __fdividef(1.f, 1.f + e);
        float val = fmaf(sg, vm, vc);

        int vi = __float_as_int(val);
        float a1 = __int_as_float(__builtin_amdgcn_ds_bpermute(idx1, vi)); // row^1
        float a2 = __int_as_float(__builtin_amdgcn_ds_bpermute(idx2, vi)); // row^2
        float a3 = __int_as_float(__builtin_amdgcn_ds_bpermute(idx3, vi)); // row^3

        float fv = q2 ? (q1 ? a3 : a2) : (q1 ? a1 : val);
        float iv = q2 ? (q1 ? a2 : a3) : (q1 ? val : a1);
        float gv = q2 ? (q1 ? a1 : val) : (q1 ? a3 : a2);
        float ov = q2 ? (q1 ? val : a1) : (q1 ? a2 : a3);

        cx = fmaf(fv, cx, iv * gv);          // valid on r==0 lanes
        float e2 = __expf(cx + cx);
        float th = 1.f - __fdividef(2.f, 1.f + e2);
        hv = ov * th;

        if (r == 0 && act) outp[(size_t)t * (BATCH * NW)] = hv;

        // broadcast hx (r==0 lanes 0..9) -> uniform SGPRs
#pragma unroll
        for (int j = 0; j < NW; ++j)
            hx_s[j] = __int_as_float(__builtin_amdgcn_readlane(__float_as_int(hv), j));

        zc = zn;
    }

    if (r == 0 && act) {
        hxout[b * NW + o] = hv;
        cxout[b * NW + o] = cx;
    }
}

extern "C" void kernel_launch(void* const* d_in, const int* in_sizes, int n_in,
                              void* d_out, int out_size, void* d_ws, size_t ws_size,
                              hipStream_t stream) {
    const float* x     = (const float*)d_in[0];  // (64,256,246)
    const float* W     = (const float*)d_in[1];  // (4,10,256)
    const float* bias  = (const float*)d_in[2];  // (4,10)
    const float* theta = (const float*)d_in[3];  // (4,10)

    float* out   = (float*)d_out;                        // (64,256,10)
    float* hxout = out + (size_t)TSTEPS * BATCH * NW;    // (256,10)
    float* cxout = hxout + (size_t)BATCH * NW;           // (256,10)

    float* zxT = (float*)d_ws;                 // (256,64,40) = 2.62 MB + 160B slack

    dim3 g1(TSTEPS, 4);
    k_gemm<<<g1, 512, 0, stream>>>(x, W, bias, theta, zxT);
    k_scan<<<BATCH / 8, 512, 0, stream>>>(zxT, W, out, hxout, cxout);
}